// Round 8
// baseline (343.826 us; speedup 1.0000x reference)
//
#include <hip/hip_runtime.h>
#include <hip/hip_bf16.h>

typedef unsigned short u16;
typedef unsigned int u32;
typedef short bf16x8 __attribute__((ext_vector_type(8)));
typedef float f32x4 __attribute__((ext_vector_type(4)));

#define NTOK 8192
#define HID 768
#define INTER 2048
#define NEXP 8

#define MFMA16(a, b, c) __builtin_amdgcn_mfma_f32_16x16x32_bf16(a, b, c, 0, 0, 0)
#define S_BARRIER() __builtin_amdgcn_s_barrier()
#define WAITVM(n) asm volatile("s_waitcnt vmcnt(" #n ")" ::: "memory")

__device__ __forceinline__ u16 f2bf(float f) {
    u32 u = __builtin_bit_cast(u32, f);
    u32 r = (u + 0x7FFFu + ((u >> 16) & 1u)) >> 16;
    return (u16)r;
}

__device__ __forceinline__ void gld16(const void* g, void* l) {
    __builtin_amdgcn_global_load_lds((const __attribute__((address_space(1))) void*)g,
                                     (__attribute__((address_space(3))) void*)l, 16, 0, 0);
}

// ---------------- zero out ----------------
__global__ __launch_bounds__(256) void zero_kernel(float4* out4, int n4) {
    int i = blockIdx.x * blockDim.x + threadIdx.x;
    float4 z = {0.f, 0.f, 0.f, 0.f};
    int stride = gridDim.x * blockDim.x;
    for (int k = i; k < n4; k += stride) out4[k] = z;
}

// ---------------- fp32 -> bf16 convert ----------------
__global__ __launch_bounds__(256) void cvt_kernel(const float* __restrict__ src, u16* __restrict__ dst, int n8) {
    int i = blockIdx.x * blockDim.x + threadIdx.x;
    int stride = gridDim.x * blockDim.x;
    for (; i < n8; i += stride) {
        const float4* s = (const float4*)(src + (size_t)i * 8);
        float4 a = s[0], b = s[1];
        u16 r[8] = {f2bf(a.x), f2bf(a.y), f2bf(a.z), f2bf(a.w),
                    f2bf(b.x), f2bf(b.y), f2bf(b.z), f2bf(b.w)};
        *(uint4*)(dst + (size_t)i * 8) = *(const uint4*)r;
    }
}

// ---------------- router: logits, top-2, softmax (NO atomics) ----------------
__global__ __launch_bounds__(256) void router2(const float* __restrict__ x, const float* __restrict__ rw,
                                               u32* __restrict__ route, float* __restrict__ wslot) {
    int wv = threadIdx.x >> 6, ln = threadIdx.x & 63;
    int t = blockIdx.x * 4 + wv;
    if (t >= NTOK) return;
    float xr[12];
#pragma unroll
    for (int j = 0; j < 12; j++) xr[j] = x[(size_t)t * HID + ln + j * 64];
    float lg[NEXP];
#pragma unroll
    for (int e = 0; e < NEXP; e++) {
        float a = 0.f;
#pragma unroll
        for (int j = 0; j < 12; j++) a += xr[j] * rw[e * HID + ln + j * 64];
#pragma unroll
        for (int off = 32; off; off >>= 1) a += __shfl_xor(a, off);
        lg[e] = a;
    }
    int i0 = 0;
    float v0 = lg[0];
#pragma unroll
    for (int e = 1; e < NEXP; e++)
        if (lg[e] > v0) { v0 = lg[e]; i0 = e; }
    int i1 = -1;
    float v1 = -1e30f;
#pragma unroll
    for (int e = 0; e < NEXP; e++) {
        if (e == i0) continue;
        if (lg[e] > v1) { v1 = lg[e]; i1 = e; }
    }
    float w0 = 1.f / (1.f + __expf(v1 - v0));
    float w1 = 1.f - w0;
    if (ln == 0) {
        wslot[0 * NTOK + t] = w0;
        wslot[1 * NTOK + t] = w1;
        route[t] = (u32)i0 | ((u32)i1 << 8);
    }
}

// ---------------- scatter: deterministic counting sort + fused schedule ----------------
__global__ __launch_bounds__(1024) void scatter_kernel(const u32* __restrict__ route, int* __restrict__ counts,
                                                       int* __restrict__ tokslot, int* __restrict__ ntiles,
                                                       int* __restrict__ tiledesc) {
    __shared__ int sc[NEXP][1024];
    int tid = threadIdx.x;
    u32 rt[8];
    int cnt[NEXP] = {0, 0, 0, 0, 0, 0, 0, 0};
#pragma unroll
    for (int k = 0; k < 8; k++) {
        rt[k] = route[tid * 8 + k];
        cnt[rt[k] & 255]++;
        cnt[(rt[k] >> 8) & 255]++;
    }
#pragma unroll
    for (int e = 0; e < NEXP; e++) sc[e][tid] = cnt[e];
    __syncthreads();
    for (int off = 1; off < 1024; off <<= 1) {
        int v[NEXP];
#pragma unroll
        for (int e = 0; e < NEXP; e++) v[e] = (tid >= off) ? sc[e][tid - off] : 0;
        __syncthreads();
#pragma unroll
        for (int e = 0; e < NEXP; e++)
            if (tid >= off) sc[e][tid] += v[e];
        __syncthreads();
    }
    int base[NEXP];
#pragma unroll
    for (int e = 0; e < NEXP; e++) base[e] = sc[e][tid] - cnt[e];
#pragma unroll
    for (int k = 0; k < 8; k++) {
        int t = tid * 8 + k;
        int e0 = rt[k] & 255, e1 = (rt[k] >> 8) & 255;
        tokslot[e0 * NTOK + base[e0]] = t;
        base[e0]++;
        tokslot[e1 * NTOK + base[e1]] = t | (1 << 16);
        base[e1]++;
    }
    if (tid == 0) {
        int tot = 0;
        for (int e = 0; e < NEXP; e++) {
            int c = sc[e][1023];
            counts[e] = c;
            int nt = (c + 255) >> 8;
            for (int q = 0; q < nt; q++) tiledesc[tot++] = (e << 8) | q;
        }
        ntiles[0] = tot;
    }
}

// =====================================================================
// m97-style multi-block GEMM: 256 threads (4 waves, 2x2), BK=32,
// LDS 48 KiB dbuf (A 16K + B 8K per buf) -> 2 blocks/CU co-resident
// (__launch_bounds__(256,2); VGPR ~205). Cross-BLOCK overlap hides the
// per-iter vmcnt(0) drain (m114/m97 mechanism) instead of intra-block
// scheduling (R5-R7 all pinned at ~9 B/cyc/CU ingest).
// Loop: STAGE(t+1) -> ds_read frags -> 32 MFMA/wave -> vmcnt(0) -> bar.
// Swizzle (64B rows, 4x16B slots): slot ^= (row&3)^((row>>2)&3) applied
// to global source (LDS dest linear, involution) and ds_read address.
// =====================================================================

#define STG(d, kt)                                           \
    do {                                                     \
        char* base_ = lds + (d)*24576 + (tid << 4);          \
        size_t ko_ = (size_t)(kt)*64;                        \
        gld16(aP[0] + ko_, base_);                           \
        gld16(aP[1] + ko_, base_ + 4096);                    \
        gld16(aP[2] + ko_, base_ + 8192);                    \
        gld16(aP[3] + ko_, base_ + 12288);                   \
        gld16(bP[0] + ko_, base_ + 16384);                   \
        gld16(bP[1] + ko_, base_ + 20480);                   \
    } while (0)

#define PIPE_MB(NKT)                                                      \
    f32x4 acc[8][4];                                                      \
    _Pragma("unroll") for (int m_ = 0; m_ < 8; m_++)                      \
        _Pragma("unroll") for (int n_ = 0; n_ < 4; n_++) acc[m_][n_] = (f32x4)0.f; \
    const int sOff = ((g4 ^ (rsel & 3) ^ ((rsel >> 2) & 3)) << 4);        \
    const int aBase = (wr * 128 + rsel) * 64 + sOff;                      \
    const int bBase = 16384 + (wc * 64 + rsel) * 64 + sOff;               \
    STG(0, 0);                                                            \
    WAITVM(0);                                                            \
    S_BARRIER();                                                          \
    for (int t = 0; t < (NKT); ++t) {                                     \
        if (t + 1 < (NKT)) STG((t + 1) & 1, t + 1);                       \
        const char* Tb = lds + (t & 1) * 24576;                           \
        bf16x8 af[8], bfr[4];                                             \
        _Pragma("unroll") for (int m_ = 0; m_ < 8; m_++)                  \
            af[m_] = *(const bf16x8*)(Tb + aBase + m_ * 1024);            \
        _Pragma("unroll") for (int n_ = 0; n_ < 4; n_++)                  \
            bfr[n_] = *(const bf16x8*)(Tb + bBase + n_ * 1024);           \
        _Pragma("unroll") for (int m_ = 0; m_ < 8; m_++)                  \
            _Pragma("unroll") for (int n_ = 0; n_ < 4; n_++)              \
                acc[m_][n_] = MFMA16(af[m_], bfr[n_], acc[m_][n_]);       \
        WAITVM(0);                                                        \
        S_BARRIER();                                                      \
    }

// ---------------- gate_up GEMM + swiglu -> h ----------------
// tile 256 tok x 64 h-cols (128 gu rows); grid (32 col-tiles, 72 slots)
__global__ __launch_bounds__(256, 2) void gateup_mb(const u16* __restrict__ xb, const u16* __restrict__ gub,
                                                    const int* __restrict__ counts,
                                                    const int* __restrict__ ntiles, const int* __restrict__ tiledesc,
                                                    const int* __restrict__ tokslot, u16* __restrict__ h) {
    if ((int)blockIdx.y >= ntiles[0]) return;
    int td = tiledesc[blockIdx.y];
    int e = td >> 8;
    int cnt = counts[e];
    int row0 = (td & 255) * 256;
    int c0 = blockIdx.x * 64;

    extern __shared__ char lds[];
    int tid = threadIdx.x;
    int wv = tid >> 6, ln = tid & 63;
    int wr = wv >> 1, wc = wv & 1;
    int rsel = ln & 15, g4 = ln >> 4;

    // staging: thread covers A rows {0,64,128,192}+srow, B rows {0,64}+srow
    int srow = tid >> 2, sl = tid & 3;
    int sswz = ((sl ^ (srow & 3) ^ ((srow >> 2) & 3)) << 4);
    const char* aP[4];
    const char* bP[2];
#pragma unroll
    for (int c = 0; c < 4; c++) {
        int gr = row0 + c * 64 + srow;
        gr = gr < cnt ? gr : cnt - 1;
        int tok = tokslot[e * NTOK + gr] & 0xFFFF;
        aP[c] = (const char*)xb + (size_t)tok * (HID * 2) + sswz;
    }
#pragma unroll
    for (int c = 0; c < 2; c++) {
        int r = c * 64 + srow;
        // B row r: wi=r&63; wi<32 -> gate col c0+(r>>6)*32+wi, else up (+2048)
        int wi = r & 63;
        int b = (wi >> 5) * 2048 + c0 + (r >> 6) * 32 + (wi & 31);
        bP[c] = (const char*)gub + ((size_t)e * 4096 + b) * (HID * 2) + sswz;
    }

    PIPE_MB(HID / 32)  // 24 K-tiles

    // epilogue: n in {0,1}=gate, n+2=up; h-col = c0 + wc*32 + n*16 + rsel
#pragma unroll
    for (int mg = 0; mg < 8; mg++) {
#pragma unroll
        for (int j = 0; j < 4; j++) {
            int gr = row0 + wr * 128 + mg * 16 + g4 * 4 + j;
            if (gr >= cnt) continue;
            int ts = tokslot[e * NTOK + gr];
            int tok = ts & 0xFFFF, slot = ts >> 16;
            u16* hrow = h + (size_t)(slot * NTOK + tok) * INTER;
#pragma unroll
            for (int n = 0; n < 2; n++) {
                float gv = acc[mg][n][j];
                float uv = fminf(acc[mg][n + 2][j], 7.0f);
                float sg = gv / (1.0f + __expf(-gv));
                hrow[c0 + wc * 32 + n * 16 + rsel] = f2bf(sg * uv);
            }
        }
    }
}

// ---------------- down GEMM + weighted atomic scatter-add ----------------
// tile 256 rows x 128 out-cols; grid (6 col-tiles, 72 slots)
__global__ __launch_bounds__(256, 2) void down_mb(const u16* __restrict__ hb, const u16* __restrict__ dnb,
                                                  const int* __restrict__ counts,
                                                  const int* __restrict__ ntiles, const int* __restrict__ tiledesc,
                                                  const int* __restrict__ tokslot,
                                                  const float* __restrict__ wslot, float* __restrict__ out) {
    if ((int)blockIdx.y >= ntiles[0]) return;
    int td = tiledesc[blockIdx.y];
    int e = td >> 8;
    int cnt = counts[e];
    int row0 = (td & 255) * 256;
    int col0 = blockIdx.x * 128;

    extern __shared__ char lds[];
    int tid = threadIdx.x;
    int wv = tid >> 6, ln = tid & 63;
    int wr = wv >> 1, wc = wv & 1;
    int rsel = ln & 15, g4 = ln >> 4;

    int srow = tid >> 2, sl = tid & 3;
    int sswz = ((sl ^ (srow & 3) ^ ((srow >> 2) & 3)) << 4);
    const char* aP[4];
    const char* bP[2];
#pragma unroll
    for (int c = 0; c < 4; c++) {
        int gr = row0 + c * 64 + srow;
        gr = gr < cnt ? gr : cnt - 1;
        int ts = tokslot[e * NTOK + gr];
        aP[c] = (const char*)hb + (size_t)((ts >> 16) * NTOK + (ts & 0xFFFF)) * (INTER * 2) + sswz;
    }
#pragma unroll
    for (int c = 0; c < 2; c++) {
        int r = c * 64 + srow;
        bP[c] = (const char*)dnb + ((size_t)e * HID + col0 + r) * (INTER * 2) + sswz;
    }

    PIPE_MB(INTER / 32)  // 64 K-tiles

#pragma unroll
    for (int mg = 0; mg < 8; mg++) {
#pragma unroll
        for (int j = 0; j < 4; j++) {
            int gr = row0 + wr * 128 + mg * 16 + g4 * 4 + j;
            if (gr >= cnt) continue;
            int ts = tokslot[e * NTOK + gr];
            int tok = ts & 0xFFFF, slot = ts >> 16;
            float w = wslot[slot * NTOK + tok];
#pragma unroll
            for (int n = 0; n < 4; n++) {
                int col = col0 + wc * 64 + n * 16 + rsel;
                atomicAdd(&out[(size_t)tok * HID + col], w * acc[mg][n][j]);
            }
        }
    }
}

// ---------------- launch ----------------
extern "C" void kernel_launch(void* const* d_in, const int* in_sizes, int n_in,
                              void* d_out, int out_size, void* d_ws, size_t ws_size,
                              hipStream_t stream) {
    const float* x = (const float*)d_in[0];
    const float* rw = (const float*)d_in[1];
    const float* gu = (const float*)d_in[2];
    const float* dn = (const float*)d_in[3];
    float* out = (float*)d_out;
    char* ws = (char*)d_ws;

    // workspace layout (bytes)
    int* counts = (int*)(ws + 0);            // 32
    int* ntiles = (int*)(ws + 64);           // 4
    int* tiledesc = (int*)(ws + 128);        // 72*4 -> ends 416
    int* tokslot = (int*)(ws + 512);         // 8*8192*4 -> ends 262656
    float* wslot = (float*)(ws + 262656);    // 2*8192*4 -> ends 328192
    u16* xb = (u16*)(ws + 328192);           // 12,582,912 -> ends 12,911,104
    u16* gub = (u16*)(ws + 12911104);        // 50,331,648 -> ends 63,242,752
    u16* dnb = (u16*)(ws + 63242752);        // 25,165,824 -> ends 88,408,576
    u16* hb = (u16*)(ws + 88408576);         // 67,108,864 -> ends 155,517,440
    // route aliases the head of hb: written by router2, consumed by scatter,
    // then hb is (re)written by gateup_mb strictly afterwards on the stream.
    u32* route = (u32*)(ws + 88408576);      // 8192*4

    zero_kernel<<<1024, 256, 0, stream>>>((float4*)out, NTOK * HID / 4);
    cvt_kernel<<<2048, 256, 0, stream>>>(x, xb, NTOK * HID / 8);
    cvt_kernel<<<2048, 256, 0, stream>>>(gu, gub, NEXP * 2 * INTER * HID / 8);
    cvt_kernel<<<2048, 256, 0, stream>>>(dn, dnb, NEXP * HID * INTER / 8);
    router2<<<NTOK / 4, 256, 0, stream>>>(x, rw, route, wslot);
    scatter_kernel<<<1, 1024, 0, stream>>>(route, counts, tokslot, ntiles, tiledesc);
    gateup_mb<<<dim3(32, 72), 256, 49152, stream>>>(xb, gub, counts, ntiles, tiledesc, tokslot, hb);
    down_mb<<<dim3(6, 72), 256, 49152, stream>>>(hb, dnb, counts, ntiles, tiledesc, tokslot, wslot, out);
}

// Round 9
// 314.727 us; speedup vs baseline: 1.0925x; 1.0925x over previous
//
#include <hip/hip_runtime.h>
#include <hip/hip_bf16.h>

typedef unsigned short u16;
typedef unsigned int u32;
typedef short bf16x8 __attribute__((ext_vector_type(8)));
typedef float f32x4 __attribute__((ext_vector_type(4)));

#define NTOK 8192
#define HID 768
#define INTER 2048
#define NEXP 8

#define MFMA16(a, b, c) __builtin_amdgcn_mfma_f32_16x16x32_bf16(a, b, c, 0, 0, 0)
#define S_BARRIER() __builtin_amdgcn_s_barrier()
#define WAITVM(n) asm volatile("s_waitcnt vmcnt(" #n ")" ::: "memory")

__device__ __forceinline__ u16 f2bf(float f) {
    u32 u = __builtin_bit_cast(u32, f);
    u32 r = (u + 0x7FFFu + ((u >> 16) & 1u)) >> 16;
    return (u16)r;
}

__device__ __forceinline__ void gld16(const void* g, void* l) {
    __builtin_amdgcn_global_load_lds((const __attribute__((address_space(1))) void*)g,
                                     (__attribute__((address_space(3))) void*)l, 16, 0, 0);
}

// ---------------- fp32 -> bf16 convert ----------------
__global__ __launch_bounds__(256) void cvt_kernel(const float* __restrict__ src, u16* __restrict__ dst, int n8) {
    int i = blockIdx.x * blockDim.x + threadIdx.x;
    int stride = gridDim.x * blockDim.x;
    for (; i < n8; i += stride) {
        const float4* s = (const float4*)(src + (size_t)i * 8);
        float4 a = s[0], b = s[1];
        u16 r[8] = {f2bf(a.x), f2bf(a.y), f2bf(a.z), f2bf(a.w),
                    f2bf(b.x), f2bf(b.y), f2bf(b.z), f2bf(b.w)};
        *(uint4*)(dst + (size_t)i * 8) = *(const uint4*)r;
    }
}

// ---------------- router: logits, top-2, softmax + fused out-zeroing ----------------
__global__ __launch_bounds__(256) void router2z(const float* __restrict__ x, const float* __restrict__ rw,
                                                u32* __restrict__ route, float* __restrict__ wslot,
                                                float4* __restrict__ out4) {
    int wv = threadIdx.x >> 6, ln = threadIdx.x & 63;
    int t = blockIdx.x * 4 + wv;
    if (t >= NTOK) return;
    // zero this token's output row (768 f32 = 192 float4)
    float4 z = {0.f, 0.f, 0.f, 0.f};
#pragma unroll
    for (int k = 0; k < 3; k++) out4[(size_t)t * 192 + ln + k * 64] = z;
    float xr[12];
#pragma unroll
    for (int j = 0; j < 12; j++) xr[j] = x[(size_t)t * HID + ln + j * 64];
    float lg[NEXP];
#pragma unroll
    for (int e = 0; e < NEXP; e++) {
        float a = 0.f;
#pragma unroll
        for (int j = 0; j < 12; j++) a += xr[j] * rw[e * HID + ln + j * 64];
#pragma unroll
        for (int off = 32; off; off >>= 1) a += __shfl_xor(a, off);
        lg[e] = a;
    }
    int i0 = 0;
    float v0 = lg[0];
#pragma unroll
    for (int e = 1; e < NEXP; e++)
        if (lg[e] > v0) { v0 = lg[e]; i0 = e; }
    int i1 = -1;
    float v1 = -1e30f;
#pragma unroll
    for (int e = 0; e < NEXP; e++) {
        if (e == i0) continue;
        if (lg[e] > v1) { v1 = lg[e]; i1 = e; }
    }
    float w0 = 1.f / (1.f + __expf(v1 - v0));
    float w1 = 1.f - w0;
    if (ln == 0) {
        wslot[0 * NTOK + t] = w0;
        wslot[1 * NTOK + t] = w1;
        route[t] = (u32)i0 | ((u32)i1 << 8);
    }
}

// ---------------- scatter: deterministic counting sort + fused schedule ----------------
__global__ __launch_bounds__(1024) void scatter_kernel(const u32* __restrict__ route, int* __restrict__ counts,
                                                       int* __restrict__ tokslot, int* __restrict__ ntiles,
                                                       int* __restrict__ tiledesc, int* __restrict__ ebase) {
    __shared__ int sc[NEXP][1024];
    int tid = threadIdx.x;
    u32 rt[8];
    int cnt[NEXP] = {0, 0, 0, 0, 0, 0, 0, 0};
#pragma unroll
    for (int k = 0; k < 8; k++) {
        rt[k] = route[tid * 8 + k];
        cnt[rt[k] & 255]++;
        cnt[(rt[k] >> 8) & 255]++;
    }
#pragma unroll
    for (int e = 0; e < NEXP; e++) sc[e][tid] = cnt[e];
    __syncthreads();
    for (int off = 1; off < 1024; off <<= 1) {
        int v[NEXP];
#pragma unroll
        for (int e = 0; e < NEXP; e++) v[e] = (tid >= off) ? sc[e][tid - off] : 0;
        __syncthreads();
#pragma unroll
        for (int e = 0; e < NEXP; e++)
            if (tid >= off) sc[e][tid] += v[e];
        __syncthreads();
    }
    int base[NEXP];
#pragma unroll
    for (int e = 0; e < NEXP; e++) base[e] = sc[e][tid] - cnt[e];
#pragma unroll
    for (int k = 0; k < 8; k++) {
        int t = tid * 8 + k;
        int e0 = rt[k] & 255, e1 = (rt[k] >> 8) & 255;
        tokslot[e0 * NTOK + base[e0]] = t;
        base[e0]++;
        tokslot[e1 * NTOK + base[e1]] = t | (1 << 16);
        base[e1]++;
    }
    if (tid == 0) {
        int tot = 0, b = 0;
        for (int e = 0; e < NEXP; e++) {
            int c = sc[e][1023];
            counts[e] = c;
            ebase[e] = b;
            b += c;
            int nt = (c + 255) >> 8;
            for (int q = 0; q < nt; q++) tiledesc[tot++] = (e << 8) | q;
        }
        ntiles[0] = tot;
    }
}

// =====================================================================
// m97-style multi-block GEMM: 256 threads (4 waves, 2x2), BK=32,
// LDS 48 KiB dbuf -> __launch_bounds__(256,3): 3 blocks/CU co-resident
// (VGPR 88 + 64 acc = 152/wave; 3x152=456 <= 512/SIMD; LDS 3x48=144K).
// Cross-BLOCK overlap hides the per-iter vmcnt(0) drain (m114 mechanism);
// R8 measured ingest 8.8 -> 12.5 B/cyc going 1->2 blocks.
// Loop: STAGE(t+1) -> ds_read frags -> 32 MFMA/wave -> vmcnt(0) -> bar.
// Swizzle: slot ^= (row&3)^((row>>2)&3) on global source + ds_read addr.
// Residual 2-way b128 phase conflict (4 slots < 8 lanes/cyc) accepted:
// off critical path at 2-phase structure (m252).
// =====================================================================

#define STG(d, kt)                                           \
    do {                                                     \
        char* base_ = lds + (d)*24576 + (tid << 4);          \
        size_t ko_ = (size_t)(kt)*64;                        \
        gld16(aP[0] + ko_, base_);                           \
        gld16(aP[1] + ko_, base_ + 4096);                    \
        gld16(aP[2] + ko_, base_ + 8192);                    \
        gld16(aP[3] + ko_, base_ + 12288);                   \
        gld16(bP[0] + ko_, base_ + 16384);                   \
        gld16(bP[1] + ko_, base_ + 20480);                   \
    } while (0)

#define PIPE_MB(NKT)                                                      \
    f32x4 acc[8][4];                                                      \
    _Pragma("unroll") for (int m_ = 0; m_ < 8; m_++)                      \
        _Pragma("unroll") for (int n_ = 0; n_ < 4; n_++) acc[m_][n_] = (f32x4)0.f; \
    const int sOff = ((g4 ^ (rsel & 3) ^ ((rsel >> 2) & 3)) << 4);        \
    const int aBase = (wr * 128 + rsel) * 64 + sOff;                      \
    const int bBase = 16384 + (wc * 64 + rsel) * 64 + sOff;               \
    STG(0, 0);                                                            \
    WAITVM(0);                                                            \
    S_BARRIER();                                                          \
    for (int t = 0; t < (NKT); ++t) {                                     \
        if (t + 1 < (NKT)) STG((t + 1) & 1, t + 1);                       \
        const char* Tb = lds + (t & 1) * 24576;                           \
        bf16x8 af[8], bfr[4];                                             \
        _Pragma("unroll") for (int m_ = 0; m_ < 8; m_++)                  \
            af[m_] = *(const bf16x8*)(Tb + aBase + m_ * 1024);            \
        _Pragma("unroll") for (int n_ = 0; n_ < 4; n_++)                  \
            bfr[n_] = *(const bf16x8*)(Tb + bBase + n_ * 1024);           \
        _Pragma("unroll") for (int m_ = 0; m_ < 8; m_++)                  \
            _Pragma("unroll") for (int n_ = 0; n_ < 4; n_++)              \
                acc[m_][n_] = MFMA16(af[m_], bfr[n_], acc[m_][n_]);       \
        WAITVM(0);                                                        \
        S_BARRIER();                                                      \
    }

// ---------------- gate_up GEMM + swiglu -> h (by expert-position) ----------------
// tile 256 tok x 64 h-cols (128 gu rows); grid (32 col-tiles, 72 slots)
__global__ __launch_bounds__(256, 3) void gateup_mb(const u16* __restrict__ xb, const u16* __restrict__ gub,
                                                    const int* __restrict__ counts,
                                                    const int* __restrict__ ntiles, const int* __restrict__ tiledesc,
                                                    const int* __restrict__ tokslot, const int* __restrict__ ebase,
                                                    u16* __restrict__ h) {
    if ((int)blockIdx.y >= ntiles[0]) return;
    int td = tiledesc[blockIdx.y];
    int e = td >> 8;
    int cnt = counts[e];
    int eb = ebase[e];
    int row0 = (td & 255) * 256;
    int c0 = blockIdx.x * 64;

    extern __shared__ char lds[];
    int tid = threadIdx.x;
    int wv = tid >> 6, ln = tid & 63;
    int wr = wv >> 1, wc = wv & 1;
    int rsel = ln & 15, g4 = ln >> 4;

    int srow = tid >> 2, sl = tid & 3;
    int sswz = ((sl ^ (srow & 3) ^ ((srow >> 2) & 3)) << 4);
    const char* aP[4];
    const char* bP[2];
#pragma unroll
    for (int c = 0; c < 4; c++) {
        int gr = row0 + c * 64 + srow;
        gr = gr < cnt ? gr : cnt - 1;
        int tok = tokslot[e * NTOK + gr] & 0xFFFF;
        aP[c] = (const char*)xb + (size_t)tok * (HID * 2) + sswz;
    }
#pragma unroll
    for (int c = 0; c < 2; c++) {
        int r = c * 64 + srow;
        int wi = r & 63;
        int b = (wi >> 5) * 2048 + c0 + (r >> 6) * 32 + (wi & 31);
        bP[c] = (const char*)gub + ((size_t)e * 4096 + b) * (HID * 2) + sswz;
    }

    PIPE_MB(HID / 32)  // 24 K-tiles

    // epilogue: n in {0,1}=gate, n+2=up; write h by expert-position (contiguous)
#pragma unroll
    for (int mg = 0; mg < 8; mg++) {
#pragma unroll
        for (int j = 0; j < 4; j++) {
            int gr = row0 + wr * 128 + mg * 16 + g4 * 4 + j;
            if (gr >= cnt) continue;
            u16* hrow = h + (size_t)(eb + gr) * INTER;
#pragma unroll
            for (int n = 0; n < 2; n++) {
                float gv = acc[mg][n][j];
                float uv = fminf(acc[mg][n + 2][j], 7.0f);
                float sg = gv / (1.0f + __expf(-gv));
                hrow[c0 + wc * 32 + n * 16 + rsel] = f2bf(sg * uv);
            }
        }
    }
}

// ---------------- down GEMM + weighted atomic scatter-add ----------------
// tile 256 rows x 128 out-cols; grid (6 col-tiles, 72 slots); A contiguous
__global__ __launch_bounds__(256, 3) void down_mb(const u16* __restrict__ hb, const u16* __restrict__ dnb,
                                                  const int* __restrict__ counts,
                                                  const int* __restrict__ ntiles, const int* __restrict__ tiledesc,
                                                  const int* __restrict__ tokslot, const int* __restrict__ ebase,
                                                  const float* __restrict__ wslot, float* __restrict__ out) {
    if ((int)blockIdx.y >= ntiles[0]) return;
    int td = tiledesc[blockIdx.y];
    int e = td >> 8;
    int cnt = counts[e];
    int eb = ebase[e];
    int row0 = (td & 255) * 256;
    int col0 = blockIdx.x * 128;

    extern __shared__ char lds[];
    int tid = threadIdx.x;
    int wv = tid >> 6, ln = tid & 63;
    int wr = wv >> 1, wc = wv & 1;
    int rsel = ln & 15, g4 = ln >> 4;

    int srow = tid >> 2, sl = tid & 3;
    int sswz = ((sl ^ (srow & 3) ^ ((srow >> 2) & 3)) << 4);
    const char* aP[4];
    const char* bP[2];
#pragma unroll
    for (int c = 0; c < 4; c++) {
        int gr = row0 + c * 64 + srow;
        gr = gr < cnt ? gr : cnt - 1;
        aP[c] = (const char*)hb + (size_t)(eb + gr) * (INTER * 2) + sswz;  // contiguous positions
    }
#pragma unroll
    for (int c = 0; c < 2; c++) {
        int r = c * 64 + srow;
        bP[c] = (const char*)dnb + ((size_t)e * HID + col0 + r) * (INTER * 2) + sswz;
    }

    PIPE_MB(INTER / 32)  // 64 K-tiles

#pragma unroll
    for (int mg = 0; mg < 8; mg++) {
#pragma unroll
        for (int j = 0; j < 4; j++) {
            int gr = row0 + wr * 128 + mg * 16 + g4 * 4 + j;
            if (gr >= cnt) continue;
            int ts = tokslot[e * NTOK + gr];
            int tok = ts & 0xFFFF, slot = ts >> 16;
            float w = wslot[slot * NTOK + tok];
#pragma unroll
            for (int n = 0; n < 4; n++) {
                int col = col0 + wc * 64 + n * 16 + rsel;
                atomicAdd(&out[(size_t)tok * HID + col], w * acc[mg][n][j]);
            }
        }
    }
}

// ---------------- launch ----------------
extern "C" void kernel_launch(void* const* d_in, const int* in_sizes, int n_in,
                              void* d_out, int out_size, void* d_ws, size_t ws_size,
                              hipStream_t stream) {
    const float* x = (const float*)d_in[0];
    const float* rw = (const float*)d_in[1];
    const float* gu = (const float*)d_in[2];
    const float* dn = (const float*)d_in[3];
    float* out = (float*)d_out;
    char* ws = (char*)d_ws;

    // workspace layout (bytes)
    int* counts = (int*)(ws + 0);            // 32
    int* ntiles = (int*)(ws + 64);           // 4
    int* tiledesc = (int*)(ws + 128);        // 72*4 -> ends 416
    int* ebase = (int*)(ws + 448);           // 8*4 -> ends 480
    int* tokslot = (int*)(ws + 512);         // 8*8192*4 -> ends 262656
    float* wslot = (float*)(ws + 262656);    // 2*8192*4 -> ends 328192
    u16* xb = (u16*)(ws + 328192);           // 12,582,912 -> ends 12,911,104
    u16* gub = (u16*)(ws + 12911104);        // 50,331,648 -> ends 63,242,752
    u16* dnb = (u16*)(ws + 63242752);        // 25,165,824 -> ends 88,408,576
    u16* hb = (u16*)(ws + 88408576);         // 67,108,864 -> ends 155,517,440
    // route aliases the head of hb: written by router2z, consumed by scatter,
    // then hb is (re)written by gateup_mb strictly afterwards on the stream.
    u32* route = (u32*)(ws + 88408576);      // 8192*4

    cvt_kernel<<<2048, 256, 0, stream>>>(x, xb, NTOK * HID / 8);
    cvt_kernel<<<2048, 256, 0, stream>>>(gu, gub, NEXP * 2 * INTER * HID / 8);
    cvt_kernel<<<2048, 256, 0, stream>>>(dn, dnb, NEXP * HID * INTER / 8);
    router2z<<<NTOK / 4, 256, 0, stream>>>(x, rw, route, wslot, (float4*)out);
    scatter_kernel<<<1, 1024, 0, stream>>>(route, counts, tokslot, ntiles, tiledesc, ebase);
    gateup_mb<<<dim3(32, 72), 256, 49152, stream>>>(xb, gub, counts, ntiles, tiledesc, tokslot, ebase, hb);
    down_mb<<<dim3(6, 72), 256, 49152, stream>>>(hb, dnb, counts, ntiles, tiledesc, tokslot, ebase, wslot, out);
}